// Round 1
// baseline (42.423 us; speedup 1.0000x reference)
//
#include <hip/hip_runtime.h>

// out[r] = sum_f in[r][f]^2 * w[f]
// ROWS=16384, F=4096, fp32 in/out. Memory-bound: 256 MiB input streamed once.

#define DD_ROWS 16384
#define DD_F    4096

__global__ __launch_bounds__(256) void DiagDot_27917287424359_kernel(
    const float* __restrict__ in,
    const float* __restrict__ w,
    float* __restrict__ out) {
    const int wave = threadIdx.x >> 6;   // 0..3
    const int lane = threadIdx.x & 63;
    const int row  = (blockIdx.x << 2) + wave;

    const float4* __restrict__ rowp =
        reinterpret_cast<const float4*>(in + (size_t)row * DD_F);
    const float4* __restrict__ wp = reinterpret_cast<const float4*>(w);

    float acc = 0.0f;
    // 4096 floats / 4 (float4) = 1024 vectors; / 64 lanes = 16 per lane.
    #pragma unroll
    for (int i = 0; i < 16; ++i) {
        const int idx = lane + (i << 6);
        float4 v  = rowp[idx];
        float4 ww = wp[idx];
        acc = fmaf(v.x * v.x, ww.x, acc);
        acc = fmaf(v.y * v.y, ww.y, acc);
        acc = fmaf(v.z * v.z, ww.z, acc);
        acc = fmaf(v.w * v.w, ww.w, acc);
    }

    // wave-64 tree reduce
    #pragma unroll
    for (int off = 32; off; off >>= 1)
        acc += __shfl_down(acc, off, 64);

    if (lane == 0) out[row] = acc;
}

extern "C" void kernel_launch(void* const* d_in, const int* in_sizes, int n_in,
                              void* d_out, int out_size, void* d_ws, size_t ws_size,
                              hipStream_t stream) {
    const float* in = (const float*)d_in[0];
    const float* w  = (const float*)d_in[1];
    float* out      = (float*)d_out;
    // 4 rows per 256-thread block
    dim3 grid(DD_ROWS / 4), block(256);
    DiagDot_27917287424359_kernel<<<grid, block, 0, stream>>>(in, w, out);
}